// Round 1
// baseline (333.768 us; speedup 1.0000x reference)
//
#include <hip/hip_runtime.h>
#include <hip/hip_bf16.h>
#include <math.h>

// Problem constants
#define NPIX   25600      // H*W = 160*160
#define CDIM   256
#define SSEL   1024       // MAX_SAMPLES
#define BATCH  4
#define INV_T  10.0f      // 1/TEMP
#define RATIO  1.4285714285714286f  // TEMP/BASE_TEMP
#define THR    0.7f

// ---------------------------------------------------------------------------
// Kernel 0: pack weights.
// w1p/w2p layout: [(k4*256 + c)*4 + kk] = w[c*256 + k4*4+kk]  (coalesced f4 loads)
// wa1t layout:    [k*64 + c] = wa1[c*256 + k]
// ---------------------------------------------------------------------------
__global__ __launch_bounds__(256) void pack_weights(
    const float* __restrict__ w1, const float* __restrict__ w2,
    const float* __restrict__ wa1,
    float* __restrict__ w1p, float* __restrict__ w2p, float* __restrict__ wa1t) {
  int e = blockIdx.x * 256 + threadIdx.x;
  if (e < 65536) {
    int kk = e & 3;
    int c  = (e >> 2) & 255;
    int k4 = e >> 10;
    int src = c * 256 + k4 * 4 + kk;
    w1p[e] = w1[src];
    w2p[e] = w2[src];
  }
  if (e < 16384) {
    int c = e & 63;
    int k = e >> 6;
    wa1t[e] = wa1[c * 256 + k];
  }
}

// ---------------------------------------------------------------------------
// Kernel 1: selection (stable "valid first" order, first 1024) + zero accums.
// One block (1024 threads) per sample.
// ---------------------------------------------------------------------------
__global__ __launch_bounds__(1024) void select_kernel(
    const int* __restrict__ labels, const int* __restrict__ sp,
    int* __restrict__ idx, int* __restrict__ selv, int* __restrict__ tsp,
    float* __restrict__ denom, float* __restrict__ Prow, float* __restrict__ Ssum) {
  int b = blockIdx.x;
  int t = threadIdx.x;
  const int* lab = labels + b * NPIX;

  // zero accumulators for later kernels
  denom[b * SSEL + t] = 0.f;
  Prow[b * SSEL + t]  = 0.f;
  if (t == 0) Ssum[b] = 0.f;

  __shared__ int red[1024];
  __shared__ int wave_tot[16];
  __shared__ int base_v, base_i, Vtot;

  // pass 1: total number of valid pixels
  int local = 0;
  for (int i = t; i < NPIX; i += 1024) local += (lab[i] == 1);
  red[t] = local;
  __syncthreads();
  for (int s = 512; s > 0; s >>= 1) {
    if (t < s) red[t] += red[t + s];
    __syncthreads();
  }
  if (t == 0) { Vtot = red[0]; base_v = 0; base_i = 0; }
  __syncthreads();

  int lane = t & 63, wid = t >> 6;
  // pass 2: stable scatter. NPIX = 25 * 1024 exactly.
  for (int c0 = 0; c0 < NPIX; c0 += 1024) {
    int i = c0 + t;
    int isv = (lab[i] == 1) ? 1 : 0;
    unsigned long long mv = __ballot(isv);
    int pv_w = __popcll(mv & ((1ull << lane) - 1ull));
    int tv_w = __popcll(mv);
    if (lane == 0) wave_tot[wid] = tv_w;
    __syncthreads();
    int pv = pv_w;
    for (int w = 0; w < wid; ++w) pv += wave_tot[w];
    int totv = 0;
    for (int w = 0; w < 16; ++w) totv += wave_tot[w];
    int gslot = isv ? (base_v + pv) : (Vtot + base_i + (t - pv));
    if (gslot < SSEL) {
      idx [b * SSEL + gslot] = i;
      selv[b * SSEL + gslot] = isv;
      tsp [b * SSEL + gslot] = sp[b * NPIX + i];
    }
    __syncthreads();
    if (t == 0) { base_v += totv; base_i += (1024 - totv); }
    __syncthreads();
  }
}

// ---------------------------------------------------------------------------
// Kernel 2: gather selected pixels, run proj MLP (256->256->256, relu between),
// L2-normalize -> fn; run attn MLP (256->64 relu ->1 sigmoid) -> tw.
// One block per 16 rows, 256 threads (thread = output channel).
// ---------------------------------------------------------------------------
#define RROWS 16
__global__ __launch_bounds__(256) void mlp_kernel(
    const float* __restrict__ feats,
    const float* __restrict__ w1p, const float* __restrict__ b1,
    const float* __restrict__ w2p, const float* __restrict__ b2,
    const float* __restrict__ wa1t, const float* __restrict__ ba1,
    const float* __restrict__ wa2, const float* __restrict__ ba2,
    const int* __restrict__ idx, float* __restrict__ fn, float* __restrict__ tw) {
  int blk = blockIdx.x;
  int r0  = blk * RROWS;          // global row (b*1024 + slot)
  int b   = r0 >> 10;
  int t   = threadIdx.x;
  int lane = t & 63;

  __shared__ float xs[RROWS][256];
  __shared__ float hs[RROWS][256];
  __shared__ float apart[4][RROWS][64];
  __shared__ float nrm[RROWS];
  __shared__ int   ridx[RROWS];

  if (t < RROWS) { ridx[t] = idx[r0 + t]; nrm[t] = 0.f; }
  __syncthreads();

  // stage x: xs[r][c] = feats[b, c, pix_r]
  for (int e = t; e < RROWS * 256; e += 256) {
    int r = e >> 8, c = e & 255;
    xs[r][c] = feats[((long)b * CDIM + c) * NPIX + ridx[r]];
  }
  __syncthreads();

  const float4* xs4  = reinterpret_cast<const float4*>(&xs[0][0]);
  const float4* hs4  = reinterpret_cast<const float4*>(&hs[0][0]);
  const float4* w1p4 = reinterpret_cast<const float4*>(w1p);
  const float4* w2p4 = reinterpret_cast<const float4*>(w2p);

  // layer 1: h = relu(x @ w1.T + b1)
  float acc[RROWS];
#pragma unroll
  for (int r = 0; r < RROWS; ++r) acc[r] = 0.f;
  for (int k4 = 0; k4 < 64; ++k4) {
    float4 wv = w1p4[k4 * 256 + t];
#pragma unroll
    for (int r = 0; r < RROWS; ++r) {
      float4 xv = xs4[r * 64 + k4];
      acc[r] += xv.x * wv.x + xv.y * wv.y + xv.z * wv.z + xv.w * wv.w;
    }
  }
  {
    float bb = b1[t];
#pragma unroll
    for (int r = 0; r < RROWS; ++r) hs[r][t] = fmaxf(acc[r] + bb, 0.f);
  }
  __syncthreads();

  // layer 2: p = h @ w2.T + b2
#pragma unroll
  for (int r = 0; r < RROWS; ++r) acc[r] = 0.f;
  for (int k4 = 0; k4 < 64; ++k4) {
    float4 wv = w2p4[k4 * 256 + t];
#pragma unroll
    for (int r = 0; r < RROWS; ++r) {
      float4 xv = hs4[r * 64 + k4];
      acc[r] += xv.x * wv.x + xv.y * wv.y + xv.z * wv.z + xv.w * wv.w;
    }
  }
  float p[RROWS];
  {
    float bb = b2[t];
#pragma unroll
    for (int r = 0; r < RROWS; ++r) p[r] = acc[r] + bb;
  }

  // row norms (wave shuffle reduce + cross-wave shared atomic)
#pragma unroll
  for (int r = 0; r < RROWS; ++r) {
    float v = p[r] * p[r];
    for (int off = 32; off > 0; off >>= 1) v += __shfl_xor(v, off, 64);
    if (lane == 0) atomicAdd(&nrm[r], v);
  }
  __syncthreads();
#pragma unroll
  for (int r = 0; r < RROWS; ++r) {
    float den = fmaxf(sqrtf(nrm[r]), 1e-12f);
    fn[(long)(r0 + r) * CDIM + t] = p[r] / den;
  }

  // attn layer 1: 4 thread-quarters each cover 64 k's for 64 output channels
  {
    int ca = t & 63, q = t >> 6;
    float aacc[RROWS];
#pragma unroll
    for (int r = 0; r < RROWS; ++r) aacc[r] = 0.f;
    for (int kk = 0; kk < 64; ++kk) {
      int k = q * 64 + kk;
      float wv = wa1t[k * 64 + ca];
#pragma unroll
      for (int r = 0; r < RROWS; ++r) aacc[r] += xs[r][k] * wv;
    }
#pragma unroll
    for (int r = 0; r < RROWS; ++r) apart[q][r][ca] = aacc[r];
  }
  __syncthreads();
  if (t < 64) {
    float wv = wa2[t];
    float bb = ba1[t];
#pragma unroll
    for (int r = 0; r < RROWS; ++r) {
      float h = apart[0][r][t] + apart[1][r][t] + apart[2][r][t] + apart[3][r][t] + bb;
      h = fmaxf(h, 0.f);
      apart[0][r][t] = h * wv;
    }
  }
  __syncthreads();
  if (t < RROWS) {
    float s = ba2[0];
    for (int c2 = 0; c2 < 64; ++c2) s += apart[0][t][c2];
    tw[r0 + t] = 1.f / (1.f + expf(-s));
  }
}

// ---------------------------------------------------------------------------
// Kernel 3: tiled sim = fn @ fn.T per sample (64x64 tiles, 4x4 microtile),
// fused epilogue accumulating per-row denom D_i, P_i = sum_j pwm, and
// per-sample S = sum pwm*sim. No sim materialization.
// ---------------------------------------------------------------------------
__global__ __launch_bounds__(256) void sim_kernel(
    const float* __restrict__ fn, const float* __restrict__ tw,
    const int* __restrict__ selv, const int* __restrict__ tsp,
    float* __restrict__ denom, float* __restrict__ Prow, float* __restrict__ Ssum) {
  int ti = blockIdx.x, tj = blockIdx.y, b = blockIdx.z;
  int t = threadIdx.x;
  int tx = t & 15, ty = t >> 4;
  int i0 = ti * 64, j0 = tj * 64;
  int base = b << 10;

  __shared__ float4 As[64 * 17];
  __shared__ float4 Bs[64 * 17];
  __shared__ float dl[64], Pl[64], Sl;

  float acc[4][4];
#pragma unroll
  for (int ii = 0; ii < 4; ++ii)
#pragma unroll
    for (int jj = 0; jj < 4; ++jj) acc[ii][jj] = 0.f;

  const float4* fn4 = reinterpret_cast<const float4*>(fn);

  for (int kk = 0; kk < 4; ++kk) {
    for (int e = t; e < 1024; e += 256) {
      int r = e >> 4, k4 = e & 15;
      As[r * 17 + k4] = fn4[(long)(base + i0 + r) * 64 + kk * 16 + k4];
      Bs[r * 17 + k4] = fn4[(long)(base + j0 + r) * 64 + kk * 16 + k4];
    }
    __syncthreads();
#pragma unroll
    for (int k4 = 0; k4 < 16; ++k4) {
      float4 av[4], bv[4];
#pragma unroll
      for (int ii = 0; ii < 4; ++ii) av[ii] = As[(ty * 4 + ii) * 17 + k4];
#pragma unroll
      for (int jj = 0; jj < 4; ++jj) bv[jj] = Bs[(tx * 4 + jj) * 17 + k4];
#pragma unroll
      for (int ii = 0; ii < 4; ++ii)
#pragma unroll
        for (int jj = 0; jj < 4; ++jj)
          acc[ii][jj] += av[ii].x * bv[jj].x + av[ii].y * bv[jj].y +
                         av[ii].z * bv[jj].z + av[ii].w * bv[jj].w;
    }
    __syncthreads();
  }

  if (t == 0) Sl = 0.f;
  __syncthreads();

  int   gi[4], gj[4], si[4], sj[4], ci[4], cj[4];
  float twi[4], twj[4];
#pragma unroll
  for (int ii = 0; ii < 4; ++ii) {
    int i = i0 + ty * 4 + ii;
    gi[ii] = i; twi[ii] = tw[base + i]; si[ii] = selv[base + i]; ci[ii] = tsp[base + i];
  }
#pragma unroll
  for (int jj = 0; jj < 4; ++jj) {
    int j = j0 + tx * 4 + jj;
    gj[jj] = j; twj[jj] = tw[base + j]; sj[jj] = selv[base + j]; cj[jj] = tsp[base + j];
  }

  float dpart[4] = {0.f, 0.f, 0.f, 0.f};
  float Ppart[4] = {0.f, 0.f, 0.f, 0.f};
  float Sp = 0.f;
#pragma unroll
  for (int ii = 0; ii < 4; ++ii) {
#pragma unroll
    for (int jj = 0; jj < 4; ++jj) {
      float s = acc[ii][jj];
      if (sj[jj]) dpart[ii] += expf(s * INV_T);  // denom includes diagonal
      if (si[ii] && sj[jj] && (ci[ii] == cj[jj]) && (s > THR) && (gi[ii] != gj[jj])) {
        float pw = twi[ii] * twj[jj];
        Ppart[ii] += pw;
        Sp += pw * s;
      }
    }
  }
  // reduce across tx (16 consecutive lanes)
  for (int off = 8; off > 0; off >>= 1) {
#pragma unroll
    for (int ii = 0; ii < 4; ++ii) {
      dpart[ii] += __shfl_xor(dpart[ii], off, 16);
      Ppart[ii] += __shfl_xor(Ppart[ii], off, 16);
    }
    Sp += __shfl_xor(Sp, off, 16);
  }
  if (tx == 0) {
#pragma unroll
    for (int ii = 0; ii < 4; ++ii) {
      dl[ty * 4 + ii] = dpart[ii];   // unique row per (ty,ii): plain store
      Pl[ty * 4 + ii] = Ppart[ii];
    }
    atomicAdd(&Sl, Sp);
  }
  __syncthreads();
  if (t < 64) {
    atomicAdd(&denom[base + i0 + t], dl[t]);
    atomicAdd(&Prow [base + i0 + t], Pl[t]);
  }
  if (t == 0) atomicAdd(&Ssum[b], Sl);
}

// ---------------------------------------------------------------------------
// Kernel 4: finalize. loss_b = -(T/BT) * (S_b/T - sum_i P_i log D_i) / psum_b
// ---------------------------------------------------------------------------
__global__ __launch_bounds__(1024) void finalize_kernel(
    const float* __restrict__ denom, const float* __restrict__ Prow,
    const float* __restrict__ Ssum, float* __restrict__ out) {
  __shared__ float redP[1024], redL[1024];
  int t = threadIdx.x;
  float total = 0.f, n = 0.f;
  for (int b = 0; b < BATCH; ++b) {
    float P = Prow[b * SSEL + t];
    float D = denom[b * SSEL + t];
    redP[t] = P;
    redL[t] = P * logf(D > 0.f ? D : 1.f);
    __syncthreads();
    for (int s = 512; s > 0; s >>= 1) {
      if (t < s) { redP[t] += redP[t + s]; redL[t] += redL[t + s]; }
      __syncthreads();
    }
    if (t == 0) {
      float psum = redP[0];
      if (psum > 0.f) {
        float wls = Ssum[b] * INV_T - redL[0];
        total += -RATIO * wls / psum;
        n += 1.f;
      }
    }
    __syncthreads();
  }
  if (t == 0) out[0] = (n > 0.f) ? (total / n) : 0.f;
}

// ---------------------------------------------------------------------------
extern "C" void kernel_launch(void* const* d_in, const int* in_sizes, int n_in,
                              void* d_out, int out_size, void* d_ws, size_t ws_size,
                              hipStream_t stream) {
  const float* feats = (const float*)d_in[0];
  const int*   labels = (const int*)d_in[1];
  const int*   sp     = (const int*)d_in[2];
  const float* w1  = (const float*)d_in[3];
  const float* b1  = (const float*)d_in[4];
  const float* w2  = (const float*)d_in[5];
  const float* b2  = (const float*)d_in[6];
  const float* wa1 = (const float*)d_in[7];
  const float* ba1 = (const float*)d_in[8];
  const float* wa2 = (const float*)d_in[9];
  const float* ba2 = (const float*)d_in[10];
  float* out = (float*)d_out;

  float* W    = (float*)d_ws;
  float* w1p  = W;                    // 65536
  float* w2p  = w1p  + 65536;         // 65536
  float* wa1t = w2p  + 65536;         // 16384
  float* fn   = wa1t + 16384;         // 4*1024*256 = 1048576
  float* tw   = fn   + 1048576;       // 4096
  float* denom= tw   + 4096;          // 4096
  float* Prow = denom+ 4096;          // 4096
  float* Ssum = Prow + 4096;          // 4
  int*   idx  = (int*)(Ssum + 4);     // 4096
  int*   selv = idx  + 4096;          // 4096
  int*   tsp  = selv + 4096;          // 4096

  pack_weights<<<256, 256, 0, stream>>>(w1, w2, wa1, w1p, w2p, wa1t);
  select_kernel<<<BATCH, 1024, 0, stream>>>(labels, sp, idx, selv, tsp, denom, Prow, Ssum);
  mlp_kernel<<<(BATCH * SSEL) / RROWS, 256, 0, stream>>>(
      feats, w1p, b1, w2p, b2, wa1t, ba1, wa2, ba2, idx, fn, tw);
  sim_kernel<<<dim3(16, 16, BATCH), 256, 0, stream>>>(fn, tw, selv, tsp, denom, Prow, Ssum);
  finalize_kernel<<<1, 1024, 0, stream>>>(denom, Prow, Ssum, out);
}

// Round 2
// 275.309 us; speedup vs baseline: 1.2123x; 1.2123x over previous
//
#include <hip/hip_runtime.h>
#include <hip/hip_bf16.h>
#include <math.h>

// Problem constants
#define NPIX   25600      // H*W = 160*160
#define CDIM   256
#define SSEL   1024       // MAX_SAMPLES
#define BATCH  4
#define NCHUNK 25         // NPIX / 1024
#define INV_T  10.0f      // 1/TEMP
#define RATIO  1.4285714285714286f  // TEMP/BASE_TEMP
#define THR    0.7f

// ---------------------------------------------------------------------------
// Kernel 0: pack weights + zero accumulators.
// w1p/w2p layout: [(k4*256 + c)*4 + kk] = w[c*256 + k4*4+kk]  (coalesced f4 loads)
// wa1t layout:    [k*64 + c] = wa1[c*256 + k]
// ---------------------------------------------------------------------------
__global__ __launch_bounds__(256) void pack_weights(
    const float* __restrict__ w1, const float* __restrict__ w2,
    const float* __restrict__ wa1,
    float* __restrict__ w1p, float* __restrict__ w2p, float* __restrict__ wa1t,
    float* __restrict__ denom, float* __restrict__ Prow, float* __restrict__ Ssum) {
  int e = blockIdx.x * 256 + threadIdx.x;
  if (e < 65536) {
    int kk = e & 3;
    int c  = (e >> 2) & 255;
    int k4 = e >> 10;
    int src = c * 256 + k4 * 4 + kk;
    w1p[e] = w1[src];
    w2p[e] = w2[src];
  }
  if (e < 16384) {
    int c = e & 63;
    int k = e >> 6;
    wa1t[e] = wa1[c * 256 + k];
  }
  if (e < BATCH * SSEL) { denom[e] = 0.f; Prow[e] = 0.f; }
  if (e < BATCH) Ssum[e] = 0.f;
}

// ---------------------------------------------------------------------------
// Kernel 1a: per-chunk valid counts. Grid: BATCH*NCHUNK blocks x 256 threads.
// ---------------------------------------------------------------------------
__global__ __launch_bounds__(256) void select_count(
    const int* __restrict__ labels, int* __restrict__ counts) {
  int b = blockIdx.x / NCHUNK, ch = blockIdx.x % NCHUNK;
  int t = threadIdx.x;
  const int* lab = labels + b * NPIX + ch * 1024;
  int local = 0;
#pragma unroll
  for (int q = 0; q < 4; ++q) local += (lab[q * 256 + t] == 1);
  for (int off = 32; off > 0; off >>= 1) local += __shfl_xor(local, off, 64);
  __shared__ int ws[4];
  if ((t & 63) == 0) ws[t >> 6] = local;
  __syncthreads();
  if (t == 0) counts[blockIdx.x] = ws[0] + ws[1] + ws[2] + ws[3];
}

// ---------------------------------------------------------------------------
// Kernel 1b: stable scatter ("valid first" order, first 1024 slots).
// Grid: BATCH*NCHUNK blocks x 1024 threads.
// ---------------------------------------------------------------------------
__global__ __launch_bounds__(1024) void select_scatter(
    const int* __restrict__ labels, const int* __restrict__ sp,
    const int* __restrict__ counts,
    int* __restrict__ idx, int* __restrict__ selv, int* __restrict__ tsp) {
  int b = blockIdx.x / NCHUNK, ch = blockIdx.x % NCHUNK;
  int t = threadIdx.x;
  __shared__ int cs[NCHUNK];
  __shared__ int wave_tot[16];
  if (t < NCHUNK) cs[t] = counts[b * NCHUNK + t];
  __syncthreads();
  int Vtot = 0, vbase = 0;
#pragma unroll
  for (int c = 0; c < NCHUNK; ++c) {
    int v = cs[c];
    Vtot += v;
    if (c < ch) vbase += v;
  }
  int ibase = ch * 1024 - vbase;  // invalid slots before this chunk

  int i = ch * 1024 + t;
  int isv = (labels[b * NPIX + i] == 1) ? 1 : 0;
  int lane = t & 63, wid = t >> 6;
  unsigned long long mv = __ballot(isv);
  int pv = __popcll(mv & ((1ull << lane) - 1ull));
  if (lane == 0) wave_tot[wid] = __popcll(mv);
  __syncthreads();
  for (int w = 0; w < wid; ++w) pv += wave_tot[w];
  int gslot = isv ? (vbase + pv) : (Vtot + ibase + (t - pv));
  if (gslot < SSEL) {
    idx [b * SSEL + gslot] = i;
    selv[b * SSEL + gslot] = isv;
    tsp [b * SSEL + gslot] = sp[b * NPIX + i];
  }
}

// ---------------------------------------------------------------------------
// Kernel 2: gather selected pixels, run proj MLP (256->256->256, relu between),
// L2-normalize -> fn; run attn MLP (256->64 relu ->1 sigmoid) -> tw.
// One block per 16 rows, 256 threads (thread = output channel).
// ---------------------------------------------------------------------------
#define RROWS 16
__global__ __launch_bounds__(256) void mlp_kernel(
    const float* __restrict__ feats,
    const float* __restrict__ w1p, const float* __restrict__ b1,
    const float* __restrict__ w2p, const float* __restrict__ b2,
    const float* __restrict__ wa1t, const float* __restrict__ ba1,
    const float* __restrict__ wa2, const float* __restrict__ ba2,
    const int* __restrict__ idx, float* __restrict__ fn, float* __restrict__ tw) {
  int blk = blockIdx.x;
  int r0  = blk * RROWS;          // global row (b*1024 + slot)
  int b   = r0 >> 10;
  int t   = threadIdx.x;
  int lane = t & 63;

  __shared__ float xs[RROWS][256];
  __shared__ float hs[RROWS][256];
  __shared__ float apart[4][RROWS][64];
  __shared__ float nrm[RROWS];
  __shared__ int   ridx[RROWS];

  if (t < RROWS) { ridx[t] = idx[r0 + t]; nrm[t] = 0.f; }
  __syncthreads();

  // stage x: xs[r][c] = feats[b, c, pix_r]
  for (int e = t; e < RROWS * 256; e += 256) {
    int r = e >> 8, c = e & 255;
    xs[r][c] = feats[((long)b * CDIM + c) * NPIX + ridx[r]];
  }
  __syncthreads();

  const float4* xs4  = reinterpret_cast<const float4*>(&xs[0][0]);
  const float4* hs4  = reinterpret_cast<const float4*>(&hs[0][0]);
  const float4* w1p4 = reinterpret_cast<const float4*>(w1p);
  const float4* w2p4 = reinterpret_cast<const float4*>(w2p);

  // layer 1: h = relu(x @ w1.T + b1)
  float acc[RROWS];
#pragma unroll
  for (int r = 0; r < RROWS; ++r) acc[r] = 0.f;
  for (int k4 = 0; k4 < 64; ++k4) {
    float4 wv = w1p4[k4 * 256 + t];
#pragma unroll
    for (int r = 0; r < RROWS; ++r) {
      float4 xv = xs4[r * 64 + k4];
      acc[r] += xv.x * wv.x + xv.y * wv.y + xv.z * wv.z + xv.w * wv.w;
    }
  }
  {
    float bb = b1[t];
#pragma unroll
    for (int r = 0; r < RROWS; ++r) hs[r][t] = fmaxf(acc[r] + bb, 0.f);
  }
  __syncthreads();

  // layer 2: p = h @ w2.T + b2
#pragma unroll
  for (int r = 0; r < RROWS; ++r) acc[r] = 0.f;
  for (int k4 = 0; k4 < 64; ++k4) {
    float4 wv = w2p4[k4 * 256 + t];
#pragma unroll
    for (int r = 0; r < RROWS; ++r) {
      float4 xv = hs4[r * 64 + k4];
      acc[r] += xv.x * wv.x + xv.y * wv.y + xv.z * wv.z + xv.w * wv.w;
    }
  }
  float p[RROWS];
  {
    float bb = b2[t];
#pragma unroll
    for (int r = 0; r < RROWS; ++r) p[r] = acc[r] + bb;
  }

  // row norms (wave shuffle reduce + cross-wave shared atomic)
#pragma unroll
  for (int r = 0; r < RROWS; ++r) {
    float v = p[r] * p[r];
    for (int off = 32; off > 0; off >>= 1) v += __shfl_xor(v, off, 64);
    if (lane == 0) atomicAdd(&nrm[r], v);
  }
  __syncthreads();
#pragma unroll
  for (int r = 0; r < RROWS; ++r) {
    float den = fmaxf(sqrtf(nrm[r]), 1e-12f);
    fn[(long)(r0 + r) * CDIM + t] = p[r] / den;
  }

  // attn layer 1: 4 thread-quarters each cover 64 k's for 64 output channels
  {
    int ca = t & 63, q = t >> 6;
    float aacc[RROWS];
#pragma unroll
    for (int r = 0; r < RROWS; ++r) aacc[r] = 0.f;
    for (int kk = 0; kk < 64; ++kk) {
      int k = q * 64 + kk;
      float wv = wa1t[k * 64 + ca];
#pragma unroll
      for (int r = 0; r < RROWS; ++r) aacc[r] += xs[r][k] * wv;
    }
#pragma unroll
    for (int r = 0; r < RROWS; ++r) apart[q][r][ca] = aacc[r];
  }
  __syncthreads();
  if (t < 64) {
    float wv = wa2[t];
    float bb = ba1[t];
#pragma unroll
    for (int r = 0; r < RROWS; ++r) {
      float h = apart[0][r][t] + apart[1][r][t] + apart[2][r][t] + apart[3][r][t] + bb;
      h = fmaxf(h, 0.f);
      apart[0][r][t] = h * wv;
    }
  }
  __syncthreads();
  if (t < RROWS) {
    float s = ba2[0];
    for (int c2 = 0; c2 < 64; ++c2) s += apart[0][t][c2];
    tw[r0 + t] = 1.f / (1.f + expf(-s));
  }
}

// ---------------------------------------------------------------------------
// Kernel 3: symmetric tiled sim = fn @ fn.T per sample. Only tiles tj>=ti.
// 64x64 tiles, 4x4 microtile. As row-major (broadcast reads), Bs k-major
// (conflict-free j-fragment reads). Off-diagonal tiles accumulate both
// row-sums (D_i,P_i) and col-sums (D_j,P_j); S counted twice.
// ---------------------------------------------------------------------------
__global__ __launch_bounds__(256) void sim_kernel(
    const float* __restrict__ fn, const float* __restrict__ tw,
    const int* __restrict__ selv, const int* __restrict__ tsp,
    float* __restrict__ denom, float* __restrict__ Prow, float* __restrict__ Ssum) {
  int b = blockIdx.y;
  int t = threadIdx.x;
  int tx = t & 15, ty = t >> 4;
  int lane = t & 63, w = t >> 6;

  // triangular tile mapping: blockIdx.x in [0,136) -> (ti,tj), tj>=ti
  int rem = blockIdx.x, ti = 0;
  while (rem >= (16 - ti)) { rem -= (16 - ti); ++ti; }
  int tj = ti + rem;
  bool diag = (ti == tj);
  int i0 = ti * 64, j0 = tj * 64;
  int base = b << 10;

  __shared__ __align__(16) float4 As4[64 * 17];   // [i][k4], stride 17 f4
  __shared__ __align__(16) float  Bs[64 * 68];    // [k][j],  stride 68 f
  __shared__ float drl[64], Prl[64];
  __shared__ float dclw[4][64], Pclw[4][64];
  __shared__ float swv[4];

  float acc[4][4];
#pragma unroll
  for (int ii = 0; ii < 4; ++ii)
#pragma unroll
    for (int jj = 0; jj < 4; ++jj) acc[ii][jj] = 0.f;

  const float4* fn4 = reinterpret_cast<const float4*>(fn);

  for (int kk = 0; kk < 4; ++kk) {
    for (int e = t; e < 1024; e += 256) {
      int rr = e >> 4, k4 = e & 15;
      As4[rr * 17 + k4] = fn4[(long)(base + i0 + rr) * 64 + kk * 16 + k4];
      float4 v = fn4[(long)(base + j0 + rr) * 64 + kk * 16 + k4];
      Bs[(4 * k4 + 0) * 68 + rr] = v.x;
      Bs[(4 * k4 + 1) * 68 + rr] = v.y;
      Bs[(4 * k4 + 2) * 68 + rr] = v.z;
      Bs[(4 * k4 + 3) * 68 + rr] = v.w;
    }
    __syncthreads();
#pragma unroll
    for (int k4 = 0; k4 < 16; ++k4) {
      float4 av[4];
#pragma unroll
      for (int ii = 0; ii < 4; ++ii) av[ii] = As4[(ty * 4 + ii) * 17 + k4];
      float4 bq0 = *(const float4*)&Bs[(4 * k4 + 0) * 68 + tx * 4];
      float4 bq1 = *(const float4*)&Bs[(4 * k4 + 1) * 68 + tx * 4];
      float4 bq2 = *(const float4*)&Bs[(4 * k4 + 2) * 68 + tx * 4];
      float4 bq3 = *(const float4*)&Bs[(4 * k4 + 3) * 68 + tx * 4];
      float b0[4] = {bq0.x, bq0.y, bq0.z, bq0.w};
      float b1v[4] = {bq1.x, bq1.y, bq1.z, bq1.w};
      float b2v[4] = {bq2.x, bq2.y, bq2.z, bq2.w};
      float b3v[4] = {bq3.x, bq3.y, bq3.z, bq3.w};
#pragma unroll
      for (int ii = 0; ii < 4; ++ii) {
        float4 a = av[ii];
#pragma unroll
        for (int jj = 0; jj < 4; ++jj)
          acc[ii][jj] += a.x * b0[jj] + a.y * b1v[jj] + a.z * b2v[jj] + a.w * b3v[jj];
      }
    }
    __syncthreads();
  }

  // ---- epilogue ----
  int   gi[4], gj[4], si[4], sj[4], ci[4], cj[4];
  float twi[4], twj[4];
#pragma unroll
  for (int ii = 0; ii < 4; ++ii) {
    int i = i0 + ty * 4 + ii;
    gi[ii] = i; twi[ii] = tw[base + i]; si[ii] = selv[base + i]; ci[ii] = tsp[base + i];
  }
#pragma unroll
  for (int jj = 0; jj < 4; ++jj) {
    int j = j0 + tx * 4 + jj;
    gj[jj] = j; twj[jj] = tw[base + j]; sj[jj] = selv[base + j]; cj[jj] = tsp[base + j];
  }

  float dR[4] = {0, 0, 0, 0}, PR[4] = {0, 0, 0, 0};
  float dC[4] = {0, 0, 0, 0}, PC[4] = {0, 0, 0, 0};
  float Sp = 0.f;
#pragma unroll
  for (int ii = 0; ii < 4; ++ii) {
#pragma unroll
    for (int jj = 0; jj < 4; ++jj) {
      float s = acc[ii][jj];
      float e10 = __expf(s * INV_T);
      if (sj[jj]) dR[ii] += e10;
      if (si[ii]) dC[jj] += e10;
      if (si[ii] && sj[jj] && (ci[ii] == cj[jj]) && (s > THR) && (gi[ii] != gj[jj])) {
        float pw = twi[ii] * twj[jj];
        PR[ii] += pw;
        PC[jj] += pw;
        Sp += pw * s;
      }
    }
  }

  // row reduce across tx (xor 1,2,4,8 stays within the 16-lane tx group)
  for (int off = 8; off > 0; off >>= 1) {
#pragma unroll
    for (int ii = 0; ii < 4; ++ii) {
      dR[ii] += __shfl_xor(dR[ii], off, 64);
      PR[ii] += __shfl_xor(PR[ii], off, 64);
    }
  }
  if (tx == 0) {
#pragma unroll
    for (int ii = 0; ii < 4; ++ii) {
      drl[ty * 4 + ii] = dR[ii];
      Prl[ty * 4 + ii] = PR[ii];
    }
  }
  // col reduce across ty-within-wave (xor 16,32), then stash per-wave partials
  if (!diag) {
    for (int off = 32; off >= 16; off >>= 1) {
#pragma unroll
      for (int jj = 0; jj < 4; ++jj) {
        dC[jj] += __shfl_xor(dC[jj], off, 64);
        PC[jj] += __shfl_xor(PC[jj], off, 64);
      }
    }
    if (lane < 16) {
#pragma unroll
      for (int jj = 0; jj < 4; ++jj) {
        dclw[w][lane * 4 + jj] = dC[jj];
        Pclw[w][lane * 4 + jj] = PC[jj];
      }
    }
  }
  // S reduce across full wave
  for (int off = 32; off > 0; off >>= 1) Sp += __shfl_xor(Sp, off, 64);
  if (lane == 0) swv[w] = Sp;
  __syncthreads();

  if (t < 64) {
    atomicAdd(&denom[base + i0 + t], drl[t]);
    atomicAdd(&Prow [base + i0 + t], Prl[t]);
    if (!diag) {
      float dc = dclw[0][t] + dclw[1][t] + dclw[2][t] + dclw[3][t];
      float pc = Pclw[0][t] + Pclw[1][t] + Pclw[2][t] + Pclw[3][t];
      atomicAdd(&denom[base + j0 + t], dc);
      atomicAdd(&Prow [base + j0 + t], pc);
    }
  }
  if (t == 0) {
    float St = swv[0] + swv[1] + swv[2] + swv[3];
    atomicAdd(&Ssum[b], diag ? St : 2.f * St);
  }
}

// ---------------------------------------------------------------------------
// Kernel 4: finalize. loss_b = -(T/BT) * (S_b/T - sum_i P_i log D_i) / psum_b
// One block, all 4 samples in parallel (t = b*256 + u).
// ---------------------------------------------------------------------------
__global__ __launch_bounds__(1024) void finalize_kernel(
    const float* __restrict__ denom, const float* __restrict__ Prow,
    const float* __restrict__ Ssum, float* __restrict__ out) {
  int t = threadIdx.x;
  int b = t >> 8, u = t & 255;
  float P = 0.f, L = 0.f;
#pragma unroll
  for (int q = 0; q < 4; ++q) {
    int s = u + q * 256;
    float p = Prow[b * SSEL + s];
    float D = denom[b * SSEL + s];
    P += p;
    L += p * logf(D > 0.f ? D : 1.f);
  }
  for (int off = 32; off > 0; off >>= 1) {
    P += __shfl_xor(P, off, 64);
    L += __shfl_xor(L, off, 64);
  }
  __shared__ float wP[16], wL[16];
  int lane = t & 63, w = t >> 6;
  if (lane == 0) { wP[w] = P; wL[w] = L; }
  __syncthreads();
  if (t == 0) {
    float total = 0.f, n = 0.f;
    for (int bb = 0; bb < BATCH; ++bb) {
      float psum = wP[4 * bb] + wP[4 * bb + 1] + wP[4 * bb + 2] + wP[4 * bb + 3];
      float lsum = wL[4 * bb] + wL[4 * bb + 1] + wL[4 * bb + 2] + wL[4 * bb + 3];
      if (psum > 0.f) {
        float wls = Ssum[bb] * INV_T - lsum;
        total += -RATIO * wls / psum;
        n += 1.f;
      }
    }
    out[0] = (n > 0.f) ? (total / n) : 0.f;
  }
}

// ---------------------------------------------------------------------------
extern "C" void kernel_launch(void* const* d_in, const int* in_sizes, int n_in,
                              void* d_out, int out_size, void* d_ws, size_t ws_size,
                              hipStream_t stream) {
  const float* feats = (const float*)d_in[0];
  const int*   labels = (const int*)d_in[1];
  const int*   sp     = (const int*)d_in[2];
  const float* w1  = (const float*)d_in[3];
  const float* b1  = (const float*)d_in[4];
  const float* w2  = (const float*)d_in[5];
  const float* b2  = (const float*)d_in[6];
  const float* wa1 = (const float*)d_in[7];
  const float* ba1 = (const float*)d_in[8];
  const float* wa2 = (const float*)d_in[9];
  const float* ba2 = (const float*)d_in[10];
  float* out = (float*)d_out;

  float* W    = (float*)d_ws;
  float* w1p  = W;                    // 65536
  float* w2p  = w1p  + 65536;         // 65536
  float* wa1t = w2p  + 65536;         // 16384
  float* fn   = wa1t + 16384;         // 4*1024*256 = 1048576
  float* tw   = fn   + 1048576;       // 4096
  float* denom= tw   + 4096;          // 4096
  float* Prow = denom+ 4096;          // 4096
  float* Ssum = Prow + 4096;          // 4
  int*   idx  = (int*)(Ssum + 4);     // 4096
  int*   selv = idx  + 4096;          // 4096
  int*   tsp  = selv + 4096;          // 4096
  int*   counts = tsp + 4096;         // 100

  pack_weights<<<256, 256, 0, stream>>>(w1, w2, wa1, w1p, w2p, wa1t,
                                        denom, Prow, Ssum);
  select_count<<<BATCH * NCHUNK, 256, 0, stream>>>(labels, counts);
  select_scatter<<<BATCH * NCHUNK, 1024, 0, stream>>>(labels, sp, counts,
                                                      idx, selv, tsp);
  mlp_kernel<<<(BATCH * SSEL) / RROWS, 256, 0, stream>>>(
      feats, w1p, b1, w2p, b2, wa1t, ba1, wa2, ba2, idx, fn, tw);
  sim_kernel<<<dim3(136, BATCH), 256, 0, stream>>>(fn, tw, selv, tsp,
                                                   denom, Prow, Ssum);
  finalize_kernel<<<1, 1024, 0, stream>>>(denom, Prow, Ssum, out);
}

// Round 3
// 265.487 us; speedup vs baseline: 1.2572x; 1.0370x over previous
//
#include <hip/hip_runtime.h>
#include <hip/hip_bf16.h>
#include <math.h>

// Problem constants
#define NPIX   25600      // H*W = 160*160
#define CDIM   256
#define SSEL   1024       // MAX_SAMPLES
#define BATCH  4
#define NCHUNK 25         // NPIX / 1024
#define INV_T  10.0f      // 1/TEMP
#define RATIO  1.4285714285714286f  // TEMP/BASE_TEMP
#define THR    0.7f

// ---------------------------------------------------------------------------
// Kernel 0: pack weights + zero accumulators + per-chunk valid counts.
// w1p/w2p layout: [(k4*256 + c)*4 + kk] = w[c*256 + k4*4+kk]
// wa1p layout:    [(k4*64  + c)*4 + kk] = wa1[c*256 + k4*4+kk]
// Blocks [0,100) additionally count valid labels in their chunk.
// ---------------------------------------------------------------------------
__global__ __launch_bounds__(256) void pack_weights(
    const float* __restrict__ w1, const float* __restrict__ w2,
    const float* __restrict__ wa1, const int* __restrict__ labels,
    float* __restrict__ w1p, float* __restrict__ w2p, float* __restrict__ wa1p,
    float* __restrict__ denom, float* __restrict__ Prow, float* __restrict__ Ssum,
    int* __restrict__ counts) {
  int t = threadIdx.x;
  int e = blockIdx.x * 256 + t;
  if (e < 65536) {
    int kk = e & 3;
    int c  = (e >> 2) & 255;
    int k4 = e >> 10;
    int src = c * 256 + k4 * 4 + kk;
    w1p[e] = w1[src];
    w2p[e] = w2[src];
  }
  if (e < 16384) {
    int kk = e & 3;
    int c  = (e >> 2) & 63;
    int k4 = e >> 8;
    wa1p[e] = wa1[c * 256 + k4 * 4 + kk];
  }
  if (e < BATCH * SSEL) { denom[e] = 0.f; Prow[e] = 0.f; }
  if (e < BATCH) Ssum[e] = 0.f;

  // fold: per-chunk valid counts (blocks 0..99)
  if (blockIdx.x < BATCH * NCHUNK) {
    int b = blockIdx.x / NCHUNK, ch = blockIdx.x % NCHUNK;
    const int* lab = labels + b * NPIX + ch * 1024;
    int local = 0;
#pragma unroll
    for (int q = 0; q < 4; ++q) local += (lab[q * 256 + t] == 1);
    for (int off = 32; off > 0; off >>= 1) local += __shfl_xor(local, off, 64);
    __shared__ int ws[4];
    if ((t & 63) == 0) ws[t >> 6] = local;
    __syncthreads();
    if (t == 0) counts[blockIdx.x] = ws[0] + ws[1] + ws[2] + ws[3];
  }
}

// ---------------------------------------------------------------------------
// Kernel 1: stable scatter ("valid first" order, first 1024 slots).
// Grid: BATCH*NCHUNK blocks x 1024 threads.
// ---------------------------------------------------------------------------
__global__ __launch_bounds__(1024) void select_scatter(
    const int* __restrict__ labels, const int* __restrict__ sp,
    const int* __restrict__ counts,
    int* __restrict__ idx, int* __restrict__ selv, int* __restrict__ tsp) {
  int b = blockIdx.x / NCHUNK, ch = blockIdx.x % NCHUNK;
  int t = threadIdx.x;
  __shared__ int cs[NCHUNK];
  __shared__ int wave_tot[16];
  if (t < NCHUNK) cs[t] = counts[b * NCHUNK + t];
  __syncthreads();
  int Vtot = 0, vbase = 0;
#pragma unroll
  for (int c = 0; c < NCHUNK; ++c) {
    int v = cs[c];
    Vtot += v;
    if (c < ch) vbase += v;
  }
  int ibase = ch * 1024 - vbase;  // invalid slots before this chunk

  int i = ch * 1024 + t;
  int isv = (labels[b * NPIX + i] == 1) ? 1 : 0;
  int lane = t & 63, wid = t >> 6;
  unsigned long long mv = __ballot(isv);
  int pv = __popcll(mv & ((1ull << lane) - 1ull));
  if (lane == 0) wave_tot[wid] = __popcll(mv);
  __syncthreads();
  for (int w = 0; w < wid; ++w) pv += wave_tot[w];
  int gslot = isv ? (vbase + pv) : (Vtot + ibase + (t - pv));
  if (gslot < SSEL) {
    idx [b * SSEL + gslot] = i;
    selv[b * SSEL + gslot] = isv;
    tsp [b * SSEL + gslot] = sp[b * NPIX + i];
  }
}

// ---------------------------------------------------------------------------
// Kernel 2: MLP. Thread = 2 output channels x 8 rows (wave = 8 shared rows
// x 128 channels): per k4-step 8 broadcast ds_read_b128 vs 64 FMA ->
// VALU-bound, not LDS-bound. Attn: thread = 1 ch x 4 rows, float4 k-steps.
// ---------------------------------------------------------------------------
#define RROWS 16
__global__ __launch_bounds__(256) void mlp_kernel(
    const float* __restrict__ feats,
    const float* __restrict__ w1p, const float* __restrict__ b1,
    const float* __restrict__ w2p, const float* __restrict__ b2,
    const float* __restrict__ wa1p, const float* __restrict__ ba1,
    const float* __restrict__ wa2, const float* __restrict__ ba2,
    const int* __restrict__ idx, float* __restrict__ fn, float* __restrict__ tw) {
  int r0  = blockIdx.x * RROWS;   // global row (b*1024 + slot)
  int b   = r0 >> 10;
  int t   = threadIdx.x;
  int lane = t & 63;

  __shared__ float xs[RROWS][256];
  __shared__ float hs[RROWS][256];
  __shared__ float apart[RROWS][64];
  __shared__ float nrm[RROWS];
  __shared__ int   ridx[RROWS];

  if (t < RROWS) { ridx[t] = idx[r0 + t]; nrm[t] = 0.f; }
  __syncthreads();

  // gather: consecutive lanes -> consecutive rows (sorted pixel idx, near
  // each other) for partial coalescing; c varies slowly.
  for (int e = t; e < RROWS * 256; e += 256) {
    int r = e & 15, c = e >> 4;
    xs[r][c] = feats[((long)b * CDIM + c) * NPIX + ridx[r]];
  }
  __syncthreads();

  const float4* xs4  = reinterpret_cast<const float4*>(&xs[0][0]);
  const float4* hs4  = reinterpret_cast<const float4*>(&hs[0][0]);
  const float4* w1p4 = reinterpret_cast<const float4*>(w1p);
  const float4* w2p4 = reinterpret_cast<const float4*>(w2p);
  const float4* wa1p4= reinterpret_cast<const float4*>(wa1p);

  // ---- attn layer 1: thread = channel (t&63) x 4 rows (t>>6) ----
  {
    int ca = t & 63, rg = t >> 6;
    float aacc[4] = {0.f, 0.f, 0.f, 0.f};
#pragma unroll 2
    for (int k4 = 0; k4 < 64; ++k4) {
      float4 wv = wa1p4[k4 * 64 + ca];
#pragma unroll
      for (int r = 0; r < 4; ++r) {
        float4 xv = xs4[(rg * 4 + r) * 64 + k4];
        aacc[r] += xv.x * wv.x + xv.y * wv.y + xv.z * wv.z + xv.w * wv.w;
      }
    }
    float bb = ba1[ca], w2v = wa2[ca];
#pragma unroll
    for (int r = 0; r < 4; ++r)
      apart[rg * 4 + r][ca] = fmaxf(aacc[r] + bb, 0.f) * w2v;
  }

  // ---- layer 1: h = relu(x @ w1.T + b1) ----
  int c  = t & 127;   // channels c, c+128
  int rg = t >> 7;    // rows rg*8 .. rg*8+7
  float acc[8][2];
#pragma unroll
  for (int r = 0; r < 8; ++r) { acc[r][0] = 0.f; acc[r][1] = 0.f; }
#pragma unroll 2
  for (int k4 = 0; k4 < 64; ++k4) {
    float4 w0 = w1p4[k4 * 256 + c];
    float4 w1v = w1p4[k4 * 256 + c + 128];
#pragma unroll
    for (int r = 0; r < 8; ++r) {
      float4 xv = xs4[(rg * 8 + r) * 64 + k4];
      acc[r][0] += xv.x * w0.x + xv.y * w0.y + xv.z * w0.z + xv.w * w0.w;
      acc[r][1] += xv.x * w1v.x + xv.y * w1v.y + xv.z * w1v.z + xv.w * w1v.w;
    }
  }
  {
    float bb0 = b1[c], bb1 = b1[c + 128];
#pragma unroll
    for (int r = 0; r < 8; ++r) {
      hs[rg * 8 + r][c]       = fmaxf(acc[r][0] + bb0, 0.f);
      hs[rg * 8 + r][c + 128] = fmaxf(acc[r][1] + bb1, 0.f);
    }
  }
  __syncthreads();

  // ---- layer 2: p = h @ w2.T + b2 ----
#pragma unroll
  for (int r = 0; r < 8; ++r) { acc[r][0] = 0.f; acc[r][1] = 0.f; }
#pragma unroll 2
  for (int k4 = 0; k4 < 64; ++k4) {
    float4 w0 = w2p4[k4 * 256 + c];
    float4 w1v = w2p4[k4 * 256 + c + 128];
#pragma unroll
    for (int r = 0; r < 8; ++r) {
      float4 xv = hs4[(rg * 8 + r) * 64 + k4];
      acc[r][0] += xv.x * w0.x + xv.y * w0.y + xv.z * w0.z + xv.w * w0.w;
      acc[r][1] += xv.x * w1v.x + xv.y * w1v.y + xv.z * w1v.z + xv.w * w1v.w;
    }
  }
  {
    float bb0 = b2[c], bb1 = b2[c + 128];
#pragma unroll
    for (int r = 0; r < 8; ++r) { acc[r][0] += bb0; acc[r][1] += bb1; }
  }

  // ---- row norms: full-wave reduce of p0^2+p1^2 (wave covers 128 ch) ----
#pragma unroll
  for (int r = 0; r < 8; ++r) {
    float v = acc[r][0] * acc[r][0] + acc[r][1] * acc[r][1];
    for (int off = 32; off > 0; off >>= 1) v += __shfl_xor(v, off, 64);
    if (lane == 0) atomicAdd(&nrm[rg * 8 + r], v);
  }
  __syncthreads();
#pragma unroll
  for (int r = 0; r < 8; ++r) {
    float den = fmaxf(sqrtf(nrm[rg * 8 + r]), 1e-12f);
    long ro = (long)(r0 + rg * 8 + r) * CDIM;
    fn[ro + c]       = acc[r][0] / den;
    fn[ro + c + 128] = acc[r][1] / den;
  }

  // ---- attn finalize ----
  if (t < RROWS) {
    float s = ba2[0];
    for (int c2 = 0; c2 < 64; ++c2) s += apart[t][c2];
    tw[r0 + t] = 1.f / (1.f + expf(-s));
  }
}

// ---------------------------------------------------------------------------
// Kernel 3: symmetric tiled sim = fn @ fn.T per sample. Only tiles tj>=ti.
// 64x64 tiles, 4x4 microtile. As row-major (broadcast reads), Bs k-major
// (conflict-free j-fragment reads). Off-diagonal tiles accumulate both
// row-sums (D_i,P_i) and col-sums (D_j,P_j); S counted twice.
// ---------------------------------------------------------------------------
__global__ __launch_bounds__(256) void sim_kernel(
    const float* __restrict__ fn, const float* __restrict__ tw,
    const int* __restrict__ selv, const int* __restrict__ tsp,
    float* __restrict__ denom, float* __restrict__ Prow, float* __restrict__ Ssum) {
  int b = blockIdx.y;
  int t = threadIdx.x;
  int tx = t & 15, ty = t >> 4;
  int lane = t & 63, w = t >> 6;

  // triangular tile mapping: blockIdx.x in [0,136) -> (ti,tj), tj>=ti
  int rem = blockIdx.x, ti = 0;
  while (rem >= (16 - ti)) { rem -= (16 - ti); ++ti; }
  int tj = ti + rem;
  bool diag = (ti == tj);
  int i0 = ti * 64, j0 = tj * 64;
  int base = b << 10;

  __shared__ __align__(16) float4 As4[64 * 17];   // [i][k4], stride 17 f4
  __shared__ __align__(16) float  Bs[64 * 68];    // [k][j],  stride 68 f
  __shared__ float drl[64], Prl[64];
  __shared__ float dclw[4][64], Pclw[4][64];
  __shared__ float swv[4];

  float acc[4][4];
#pragma unroll
  for (int ii = 0; ii < 4; ++ii)
#pragma unroll
    for (int jj = 0; jj < 4; ++jj) acc[ii][jj] = 0.f;

  const float4* fn4 = reinterpret_cast<const float4*>(fn);

  for (int kk = 0; kk < 4; ++kk) {
    for (int e = t; e < 1024; e += 256) {
      int rr = e >> 4, k4 = e & 15;
      As4[rr * 17 + k4] = fn4[(long)(base + i0 + rr) * 64 + kk * 16 + k4];
      float4 v = fn4[(long)(base + j0 + rr) * 64 + kk * 16 + k4];
      Bs[(4 * k4 + 0) * 68 + rr] = v.x;
      Bs[(4 * k4 + 1) * 68 + rr] = v.y;
      Bs[(4 * k4 + 2) * 68 + rr] = v.z;
      Bs[(4 * k4 + 3) * 68 + rr] = v.w;
    }
    __syncthreads();
#pragma unroll
    for (int k4 = 0; k4 < 16; ++k4) {
      float4 av[4];
#pragma unroll
      for (int ii = 0; ii < 4; ++ii) av[ii] = As4[(ty * 4 + ii) * 17 + k4];
      float4 bq0 = *(const float4*)&Bs[(4 * k4 + 0) * 68 + tx * 4];
      float4 bq1 = *(const float4*)&Bs[(4 * k4 + 1) * 68 + tx * 4];
      float4 bq2 = *(const float4*)&Bs[(4 * k4 + 2) * 68 + tx * 4];
      float4 bq3 = *(const float4*)&Bs[(4 * k4 + 3) * 68 + tx * 4];
      float b0[4] = {bq0.x, bq0.y, bq0.z, bq0.w};
      float b1v[4] = {bq1.x, bq1.y, bq1.z, bq1.w};
      float b2v[4] = {bq2.x, bq2.y, bq2.z, bq2.w};
      float b3v[4] = {bq3.x, bq3.y, bq3.z, bq3.w};
#pragma unroll
      for (int ii = 0; ii < 4; ++ii) {
        float4 a = av[ii];
#pragma unroll
        for (int jj = 0; jj < 4; ++jj)
          acc[ii][jj] += a.x * b0[jj] + a.y * b1v[jj] + a.z * b2v[jj] + a.w * b3v[jj];
      }
    }
    __syncthreads();
  }

  // ---- epilogue ----
  int   gi[4], gj[4], si[4], sj[4], ci[4], cj[4];
  float twi[4], twj[4];
#pragma unroll
  for (int ii = 0; ii < 4; ++ii) {
    int i = i0 + ty * 4 + ii;
    gi[ii] = i; twi[ii] = tw[base + i]; si[ii] = selv[base + i]; ci[ii] = tsp[base + i];
  }
#pragma unroll
  for (int jj = 0; jj < 4; ++jj) {
    int j = j0 + tx * 4 + jj;
    gj[jj] = j; twj[jj] = tw[base + j]; sj[jj] = selv[base + j]; cj[jj] = tsp[base + j];
  }

  float dR[4] = {0, 0, 0, 0}, PR[4] = {0, 0, 0, 0};
  float dC[4] = {0, 0, 0, 0}, PC[4] = {0, 0, 0, 0};
  float Sp = 0.f;
#pragma unroll
  for (int ii = 0; ii < 4; ++ii) {
#pragma unroll
    for (int jj = 0; jj < 4; ++jj) {
      float s = acc[ii][jj];
      float e10 = __expf(s * INV_T);
      if (sj[jj]) dR[ii] += e10;
      if (si[ii]) dC[jj] += e10;
      if (si[ii] && sj[jj] && (ci[ii] == cj[jj]) && (s > THR) && (gi[ii] != gj[jj])) {
        float pw = twi[ii] * twj[jj];
        PR[ii] += pw;
        PC[jj] += pw;
        Sp += pw * s;
      }
    }
  }

  // row reduce across tx (xor 1,2,4,8 stays within the 16-lane tx group)
  for (int off = 8; off > 0; off >>= 1) {
#pragma unroll
    for (int ii = 0; ii < 4; ++ii) {
      dR[ii] += __shfl_xor(dR[ii], off, 64);
      PR[ii] += __shfl_xor(PR[ii], off, 64);
    }
  }
  if (tx == 0) {
#pragma unroll
    for (int ii = 0; ii < 4; ++ii) {
      drl[ty * 4 + ii] = dR[ii];
      Prl[ty * 4 + ii] = PR[ii];
    }
  }
  // col reduce across ty-within-wave (xor 16,32), then stash per-wave partials
  if (!diag) {
    for (int off = 32; off >= 16; off >>= 1) {
#pragma unroll
      for (int jj = 0; jj < 4; ++jj) {
        dC[jj] += __shfl_xor(dC[jj], off, 64);
        PC[jj] += __shfl_xor(PC[jj], off, 64);
      }
    }
    if (lane < 16) {
#pragma unroll
      for (int jj = 0; jj < 4; ++jj) {
        dclw[w][lane * 4 + jj] = dC[jj];
        Pclw[w][lane * 4 + jj] = PC[jj];
      }
    }
  }
  // S reduce across full wave
  for (int off = 32; off > 0; off >>= 1) Sp += __shfl_xor(Sp, off, 64);
  if (lane == 0) swv[w] = Sp;
  __syncthreads();

  if (t < 64) {
    atomicAdd(&denom[base + i0 + t], drl[t]);
    atomicAdd(&Prow [base + i0 + t], Prl[t]);
    if (!diag) {
      float dc = dclw[0][t] + dclw[1][t] + dclw[2][t] + dclw[3][t];
      float pc = Pclw[0][t] + Pclw[1][t] + Pclw[2][t] + Pclw[3][t];
      atomicAdd(&denom[base + j0 + t], dc);
      atomicAdd(&Prow [base + j0 + t], pc);
    }
  }
  if (t == 0) {
    float St = swv[0] + swv[1] + swv[2] + swv[3];
    atomicAdd(&Ssum[b], diag ? St : 2.f * St);
  }
}

// ---------------------------------------------------------------------------
// Kernel 4: finalize. loss_b = -(T/BT) * (S_b/T - sum_i P_i log D_i) / psum_b
// One block, all 4 samples in parallel (t = b*256 + u).
// ---------------------------------------------------------------------------
__global__ __launch_bounds__(1024) void finalize_kernel(
    const float* __restrict__ denom, const float* __restrict__ Prow,
    const float* __restrict__ Ssum, float* __restrict__ out) {
  int t = threadIdx.x;
  int b = t >> 8, u = t & 255;
  float P = 0.f, L = 0.f;
#pragma unroll
  for (int q = 0; q < 4; ++q) {
    int s = u + q * 256;
    float p = Prow[b * SSEL + s];
    float D = denom[b * SSEL + s];
    P += p;
    L += p * logf(D > 0.f ? D : 1.f);
  }
  for (int off = 32; off > 0; off >>= 1) {
    P += __shfl_xor(P, off, 64);
    L += __shfl_xor(L, off, 64);
  }
  __shared__ float wP[16], wL[16];
  int lane = t & 63, w = t >> 6;
  if (lane == 0) { wP[w] = P; wL[w] = L; }
  __syncthreads();
  if (t == 0) {
    float total = 0.f, n = 0.f;
    for (int bb = 0; bb < BATCH; ++bb) {
      float psum = wP[4 * bb] + wP[4 * bb + 1] + wP[4 * bb + 2] + wP[4 * bb + 3];
      float lsum = wL[4 * bb] + wL[4 * bb + 1] + wL[4 * bb + 2] + wL[4 * bb + 3];
      if (psum > 0.f) {
        float wls = Ssum[bb] * INV_T - lsum;
        total += -RATIO * wls / psum;
        n += 1.f;
      }
    }
    out[0] = (n > 0.f) ? (total / n) : 0.f;
  }
}

// ---------------------------------------------------------------------------
extern "C" void kernel_launch(void* const* d_in, const int* in_sizes, int n_in,
                              void* d_out, int out_size, void* d_ws, size_t ws_size,
                              hipStream_t stream) {
  const float* feats = (const float*)d_in[0];
  const int*   labels = (const int*)d_in[1];
  const int*   sp     = (const int*)d_in[2];
  const float* w1  = (const float*)d_in[3];
  const float* b1  = (const float*)d_in[4];
  const float* w2  = (const float*)d_in[5];
  const float* b2  = (const float*)d_in[6];
  const float* wa1 = (const float*)d_in[7];
  const float* ba1 = (const float*)d_in[8];
  const float* wa2 = (const float*)d_in[9];
  const float* ba2 = (const float*)d_in[10];
  float* out = (float*)d_out;

  float* W    = (float*)d_ws;
  float* w1p  = W;                    // 65536
  float* w2p  = w1p  + 65536;         // 65536
  float* wa1p = w2p  + 65536;         // 16384
  float* fn   = wa1p + 16384;         // 4*1024*256 = 1048576
  float* tw   = fn   + 1048576;       // 4096
  float* denom= tw   + 4096;          // 4096
  float* Prow = denom+ 4096;          // 4096
  float* Ssum = Prow + 4096;          // 4
  int*   idx  = (int*)(Ssum + 4);     // 4096
  int*   selv = idx  + 4096;          // 4096
  int*   tsp  = selv + 4096;          // 4096
  int*   counts = tsp + 4096;         // 100

  pack_weights<<<256, 256, 0, stream>>>(w1, w2, wa1, labels, w1p, w2p, wa1p,
                                        denom, Prow, Ssum, counts);
  select_scatter<<<BATCH * NCHUNK, 1024, 0, stream>>>(labels, sp, counts,
                                                      idx, selv, tsp);
  mlp_kernel<<<(BATCH * SSEL) / RROWS, 256, 0, stream>>>(
      feats, w1p, b1, w2p, b2, wa1p, ba1, wa2, ba2, idx, fn, tw);
  sim_kernel<<<dim3(136, BATCH), 256, 0, stream>>>(fn, tw, selv, tsp,
                                                   denom, Prow, Ssum);
  finalize_kernel<<<1, 1024, 0, stream>>>(denom, Prow, Ssum, out);
}

// Round 4
// 222.448 us; speedup vs baseline: 1.5004x; 1.1935x over previous
//
#include <hip/hip_runtime.h>
#include <hip/hip_bf16.h>
#include <math.h>

// Problem constants
#define NPIX   25600      // H*W = 160*160
#define CDIM   256
#define SSEL   1024       // MAX_SAMPLES
#define BATCH  4
#define NCHUNK 25         // NPIX / 1024
#define INV_T  10.0f      // 1/TEMP
#define RATIO  1.4285714285714286f  // TEMP/BASE_TEMP
#define THR    0.7f

typedef __attribute__((ext_vector_type(8))) short bf16x8;
typedef __attribute__((ext_vector_type(4))) float f32x4;

// ---------------------------------------------------------------------------
// Kernel 0: pack weights + zero accumulators + per-chunk valid counts.
// ---------------------------------------------------------------------------
__global__ __launch_bounds__(256) void pack_weights(
    const float* __restrict__ w1, const float* __restrict__ w2,
    const float* __restrict__ wa1, const int* __restrict__ labels,
    float* __restrict__ w1p, float* __restrict__ w2p, float* __restrict__ wa1p,
    float* __restrict__ denom, float* __restrict__ Prow, float* __restrict__ Ssum,
    int* __restrict__ counts) {
  int t = threadIdx.x;
  int e = blockIdx.x * 256 + t;
  if (e < 65536) {
    int kk = e & 3;
    int c  = (e >> 2) & 255;
    int k4 = e >> 10;
    int src = c * 256 + k4 * 4 + kk;
    w1p[e] = w1[src];
    w2p[e] = w2[src];
  }
  if (e < 16384) {
    int kk = e & 3;
    int c  = (e >> 2) & 63;
    int k4 = e >> 8;
    wa1p[e] = wa1[c * 256 + k4 * 4 + kk];
  }
  if (e < BATCH * SSEL) { denom[e] = 0.f; Prow[e] = 0.f; }
  if (e < BATCH) Ssum[e] = 0.f;

  if (blockIdx.x < BATCH * NCHUNK) {
    int b = blockIdx.x / NCHUNK, ch = blockIdx.x % NCHUNK;
    const int* lab = labels + b * NPIX + ch * 1024;
    int local = 0;
#pragma unroll
    for (int q = 0; q < 4; ++q) local += (lab[q * 256 + t] == 1);
    for (int off = 32; off > 0; off >>= 1) local += __shfl_xor(local, off, 64);
    __shared__ int ws[4];
    if ((t & 63) == 0) ws[t >> 6] = local;
    __syncthreads();
    if (t == 0) counts[blockIdx.x] = ws[0] + ws[1] + ws[2] + ws[3];
  }
}

// ---------------------------------------------------------------------------
// Kernel 1: stable scatter ("valid first" order, first 1024 slots).
// ---------------------------------------------------------------------------
__global__ __launch_bounds__(1024) void select_scatter(
    const int* __restrict__ labels, const int* __restrict__ sp,
    const int* __restrict__ counts,
    int* __restrict__ idx, int* __restrict__ selv, int* __restrict__ tsp) {
  int b = blockIdx.x / NCHUNK, ch = blockIdx.x % NCHUNK;
  int t = threadIdx.x;
  __shared__ int cs[NCHUNK];
  __shared__ int wave_tot[16];
  if (t < NCHUNK) cs[t] = counts[b * NCHUNK + t];
  __syncthreads();
  int Vtot = 0, vbase = 0;
#pragma unroll
  for (int c = 0; c < NCHUNK; ++c) {
    int v = cs[c];
    Vtot += v;
    if (c < ch) vbase += v;
  }
  int ibase = ch * 1024 - vbase;

  int i = ch * 1024 + t;
  int isv = (labels[b * NPIX + i] == 1) ? 1 : 0;
  int lane = t & 63, wid = t >> 6;
  unsigned long long mv = __ballot(isv);
  int pv = __popcll(mv & ((1ull << lane) - 1ull));
  if (lane == 0) wave_tot[wid] = __popcll(mv);
  __syncthreads();
  for (int w = 0; w < wid; ++w) pv += wave_tot[w];
  int gslot = isv ? (vbase + pv) : (Vtot + ibase + (t - pv));
  if (gslot < SSEL) {
    idx [b * SSEL + gslot] = i;
    selv[b * SSEL + gslot] = isv;
    tsp [b * SSEL + gslot] = sp[b * NPIX + i];
  }
}

// ---------------------------------------------------------------------------
// Kernel 2: MLP. Thread = 2 output channels x 8 rows. Emits fn as split
// bf16 planes (fnh = bf16(fn), fnl = bf16(fn - fnh)) for the MFMA sim GEMM.
// ---------------------------------------------------------------------------
#define RROWS 16
__global__ __launch_bounds__(256) void mlp_kernel(
    const float* __restrict__ feats,
    const float* __restrict__ w1p, const float* __restrict__ b1,
    const float* __restrict__ w2p, const float* __restrict__ b2,
    const float* __restrict__ wa1p, const float* __restrict__ ba1,
    const float* __restrict__ wa2, const float* __restrict__ ba2,
    const int* __restrict__ idx,
    unsigned short* __restrict__ fnh, unsigned short* __restrict__ fnl,
    float* __restrict__ tw) {
  int r0  = blockIdx.x * RROWS;   // global row (b*1024 + slot)
  int b   = r0 >> 10;
  int t   = threadIdx.x;
  int lane = t & 63;

  __shared__ float xs[RROWS][256];
  __shared__ float hs[RROWS][256];
  __shared__ float apart[RROWS][64];
  __shared__ float nrm[RROWS];
  __shared__ int   ridx[RROWS];

  if (t < RROWS) { ridx[t] = idx[r0 + t]; nrm[t] = 0.f; }
  __syncthreads();

  for (int e = t; e < RROWS * 256; e += 256) {
    int r = e & 15, c = e >> 4;
    xs[r][c] = feats[((long)b * CDIM + c) * NPIX + ridx[r]];
  }
  __syncthreads();

  const float4* xs4  = reinterpret_cast<const float4*>(&xs[0][0]);
  const float4* hs4  = reinterpret_cast<const float4*>(&hs[0][0]);
  const float4* w1p4 = reinterpret_cast<const float4*>(w1p);
  const float4* w2p4 = reinterpret_cast<const float4*>(w2p);
  const float4* wa1p4= reinterpret_cast<const float4*>(wa1p);

  // ---- attn layer 1 ----
  {
    int ca = t & 63, rg = t >> 6;
    float aacc[4] = {0.f, 0.f, 0.f, 0.f};
#pragma unroll 2
    for (int k4 = 0; k4 < 64; ++k4) {
      float4 wv = wa1p4[k4 * 64 + ca];
#pragma unroll
      for (int r = 0; r < 4; ++r) {
        float4 xv = xs4[(rg * 4 + r) * 64 + k4];
        aacc[r] += xv.x * wv.x + xv.y * wv.y + xv.z * wv.z + xv.w * wv.w;
      }
    }
    float bb = ba1[ca], w2v = wa2[ca];
#pragma unroll
    for (int r = 0; r < 4; ++r)
      apart[rg * 4 + r][ca] = fmaxf(aacc[r] + bb, 0.f) * w2v;
  }

  // ---- layer 1 ----
  int c  = t & 127;
  int rg = t >> 7;
  float acc[8][2];
#pragma unroll
  for (int r = 0; r < 8; ++r) { acc[r][0] = 0.f; acc[r][1] = 0.f; }
#pragma unroll 2
  for (int k4 = 0; k4 < 64; ++k4) {
    float4 w0 = w1p4[k4 * 256 + c];
    float4 w1v = w1p4[k4 * 256 + c + 128];
#pragma unroll
    for (int r = 0; r < 8; ++r) {
      float4 xv = xs4[(rg * 8 + r) * 64 + k4];
      acc[r][0] += xv.x * w0.x + xv.y * w0.y + xv.z * w0.z + xv.w * w0.w;
      acc[r][1] += xv.x * w1v.x + xv.y * w1v.y + xv.z * w1v.z + xv.w * w1v.w;
    }
  }
  {
    float bb0 = b1[c], bb1 = b1[c + 128];
#pragma unroll
    for (int r = 0; r < 8; ++r) {
      hs[rg * 8 + r][c]       = fmaxf(acc[r][0] + bb0, 0.f);
      hs[rg * 8 + r][c + 128] = fmaxf(acc[r][1] + bb1, 0.f);
    }
  }
  __syncthreads();

  // ---- layer 2 ----
#pragma unroll
  for (int r = 0; r < 8; ++r) { acc[r][0] = 0.f; acc[r][1] = 0.f; }
#pragma unroll 2
  for (int k4 = 0; k4 < 64; ++k4) {
    float4 w0 = w2p4[k4 * 256 + c];
    float4 w1v = w2p4[k4 * 256 + c + 128];
#pragma unroll
    for (int r = 0; r < 8; ++r) {
      float4 xv = hs4[(rg * 8 + r) * 64 + k4];
      acc[r][0] += xv.x * w0.x + xv.y * w0.y + xv.z * w0.z + xv.w * w0.w;
      acc[r][1] += xv.x * w1v.x + xv.y * w1v.y + xv.z * w1v.z + xv.w * w1v.w;
    }
  }
  {
    float bb0 = b2[c], bb1 = b2[c + 128];
#pragma unroll
    for (int r = 0; r < 8; ++r) { acc[r][0] += bb0; acc[r][1] += bb1; }
  }

  // ---- row norms ----
#pragma unroll
  for (int r = 0; r < 8; ++r) {
    float v = acc[r][0] * acc[r][0] + acc[r][1] * acc[r][1];
    for (int off = 32; off > 0; off >>= 1) v += __shfl_xor(v, off, 64);
    if (lane == 0) atomicAdd(&nrm[rg * 8 + r], v);
  }
  __syncthreads();
#pragma unroll
  for (int r = 0; r < 8; ++r) {
    float den = fmaxf(sqrtf(nrm[rg * 8 + r]), 1e-12f);
    long ro = (long)(r0 + rg * 8 + r) * CDIM;
    float v0 = acc[r][0] / den;
    float v1 = acc[r][1] / den;
    __hip_bfloat16 h0 = __float2bfloat16(v0);
    __hip_bfloat16 h1 = __float2bfloat16(v1);
    __hip_bfloat16 l0 = __float2bfloat16(v0 - __bfloat162float(h0));
    __hip_bfloat16 l1 = __float2bfloat16(v1 - __bfloat162float(h1));
    fnh[ro + c]       = *reinterpret_cast<unsigned short*>(&h0);
    fnh[ro + c + 128] = *reinterpret_cast<unsigned short*>(&h1);
    fnl[ro + c]       = *reinterpret_cast<unsigned short*>(&l0);
    fnl[ro + c + 128] = *reinterpret_cast<unsigned short*>(&l1);
  }

  // ---- attn finalize ----
  if (t < RROWS) {
    float s = ba2[0];
    for (int c2 = 0; c2 < 64; ++c2) s += apart[t][c2];
    tw[r0 + t] = 1.f / (1.f + expf(-s));
  }
}

// ---------------------------------------------------------------------------
// Kernel 3: MFMA sim = fn @ fn.T (split-bf16: HH + HL + LH ~= fp32).
// Triangular tiles tj>=ti, 64x64 per block, 4 waves; wave w computes rows
// w*16..+15 x all 64 cols via 4 accumulators of mfma_f32_16x16x32_bf16.
// LDS row stride 72 ushorts -> frag reads 2-way (free).
// ---------------------------------------------------------------------------
__global__ __launch_bounds__(256) void sim_kernel(
    const unsigned short* __restrict__ fnh, const unsigned short* __restrict__ fnl,
    const float* __restrict__ tw,
    const int* __restrict__ selv, const int* __restrict__ tsp,
    float* __restrict__ denom, float* __restrict__ Prow, float* __restrict__ Ssum) {
  int b = blockIdx.y;
  int t = threadIdx.x;
  int lane = t & 63, w = t >> 6;
  int m = lane & 15, q = lane >> 4;

  // triangular tile mapping: blockIdx.x in [0,136) -> (ti,tj), tj>=ti
  int rem = blockIdx.x, ti = 0;
  while (rem >= (16 - ti)) { rem -= (16 - ti); ++ti; }
  int tj = ti + rem;
  bool diag = (ti == tj);
  int i0 = ti * 64, j0 = tj * 64;
  int base = b << 10;

  __shared__ __align__(16) unsigned short Ah[64 * 72], Al[64 * 72];
  __shared__ __align__(16) unsigned short Bhh[64 * 72], Bll[64 * 72];
  __shared__ float drl[64], Prl[64];
  __shared__ float dclw[4][64], Pclw[4][64];
  __shared__ float swv[4];

  const unsigned short* Bh = diag ? Ah : Bhh;
  const unsigned short* Bl = diag ? Al : Bll;

  f32x4 acc[4];
#pragma unroll
  for (int nt = 0; nt < 4; ++nt) acc[nt] = {0.f, 0.f, 0.f, 0.f};

  for (int kk = 0; kk < 4; ++kk) {
    __syncthreads();
#pragma unroll
    for (int p = 0; p < 2; ++p) {
      int e = p * 256 + t;
      int row = e >> 3, kg = e & 7;
      int lo = row * 72 + kg * 8;
      int gi_ = (base + i0 + row) * 256 + kk * 64 + kg * 8;
      *(uint4*)&Ah[lo] = *(const uint4*)&fnh[gi_];
      *(uint4*)&Al[lo] = *(const uint4*)&fnl[gi_];
      if (!diag) {
        int gj_ = (base + j0 + row) * 256 + kk * 64 + kg * 8;
        *(uint4*)&Bhh[lo] = *(const uint4*)&fnh[gj_];
        *(uint4*)&Bll[lo] = *(const uint4*)&fnl[gj_];
      }
    }
    __syncthreads();
#pragma unroll
    for (int ks = 0; ks < 2; ++ks) {
      int koff = ks * 32 + q * 8;           // ushort offset within row
      int arow = w * 16 + m;
      bf16x8 ah = *(const bf16x8*)&Ah[arow * 72 + koff];
      bf16x8 al = *(const bf16x8*)&Al[arow * 72 + koff];
#pragma unroll
      for (int nt = 0; nt < 4; ++nt) {
        bf16x8 bh = *(const bf16x8*)&Bh[(nt * 16 + m) * 72 + koff];
        bf16x8 bl = *(const bf16x8*)&Bl[(nt * 16 + m) * 72 + koff];
        acc[nt] = __builtin_amdgcn_mfma_f32_16x16x32_bf16(ah, bh, acc[nt], 0, 0, 0);
        acc[nt] = __builtin_amdgcn_mfma_f32_16x16x32_bf16(ah, bl, acc[nt], 0, 0, 0);
        acc[nt] = __builtin_amdgcn_mfma_f32_16x16x32_bf16(al, bh, acc[nt], 0, 0, 0);
      }
    }
  }

  // ---- epilogue ----
  // C/D layout (verified m89/m91): col = lane&15 (j), row = (lane>>4)*4+reg (i)
  int   gi[4], gj[4], si[4], sj[4], ci[4], cj[4];
  float twi[4], twj[4];
#pragma unroll
  for (int reg = 0; reg < 4; ++reg) {
    int i = i0 + w * 16 + q * 4 + reg;
    gi[reg] = i; twi[reg] = tw[base + i];
    si[reg] = selv[base + i]; ci[reg] = tsp[base + i];
  }
#pragma unroll
  for (int nt = 0; nt < 4; ++nt) {
    int j = j0 + nt * 16 + m;
    gj[nt] = j; twj[nt] = tw[base + j];
    sj[nt] = selv[base + j]; cj[nt] = tsp[base + j];
  }

  float dR[4] = {0, 0, 0, 0}, PR[4] = {0, 0, 0, 0};
  float dC[4] = {0, 0, 0, 0}, PC[4] = {0, 0, 0, 0};
  float Sp = 0.f;
#pragma unroll
  for (int nt = 0; nt < 4; ++nt) {
#pragma unroll
    for (int reg = 0; reg < 4; ++reg) {
      float s = acc[nt][reg];
      float e10 = __expf(s * INV_T);
      if (sj[nt]) dR[reg] += e10;
      if (si[reg]) dC[nt] += e10;
      if (si[reg] && sj[nt] && (ci[reg] == cj[nt]) && (s > THR) && (gi[reg] != gj[nt])) {
        float pw = twi[reg] * twj[nt];
        PR[reg] += pw;
        PC[nt] += pw;
        Sp += pw * s;
      }
    }
  }

  // row reduce across m (xor 1,2,4,8 stays within the 16-lane group)
  for (int off = 8; off > 0; off >>= 1) {
#pragma unroll
    for (int reg = 0; reg < 4; ++reg) {
      dR[reg] += __shfl_xor(dR[reg], off, 64);
      PR[reg] += __shfl_xor(PR[reg], off, 64);
    }
  }
  if (m == 0) {
#pragma unroll
    for (int reg = 0; reg < 4; ++reg) {
      drl[w * 16 + q * 4 + reg] = dR[reg];
      Prl[w * 16 + q * 4 + reg] = PR[reg];
    }
  }
  // col reduce across q (xor 16,32), then stash per-wave partials
  if (!diag) {
    for (int off = 32; off >= 16; off >>= 1) {
#pragma unroll
      for (int nt = 0; nt < 4; ++nt) {
        dC[nt] += __shfl_xor(dC[nt], off, 64);
        PC[nt] += __shfl_xor(PC[nt], off, 64);
      }
    }
    if (q == 0) {
#pragma unroll
      for (int nt = 0; nt < 4; ++nt) {
        dclw[w][nt * 16 + m] = dC[nt];
        Pclw[w][nt * 16 + m] = PC[nt];
      }
    }
  }
  // S reduce across full wave
  for (int off = 32; off > 0; off >>= 1) Sp += __shfl_xor(Sp, off, 64);
  if (lane == 0) swv[w] = Sp;
  __syncthreads();

  if (t < 64) {
    atomicAdd(&denom[base + i0 + t], drl[t]);
    atomicAdd(&Prow [base + i0 + t], Prl[t]);
    if (!diag) {
      float dc = dclw[0][t] + dclw[1][t] + dclw[2][t] + dclw[3][t];
      float pc = Pclw[0][t] + Pclw[1][t] + Pclw[2][t] + Pclw[3][t];
      atomicAdd(&denom[base + j0 + t], dc);
      atomicAdd(&Prow [base + j0 + t], pc);
    }
  }
  if (t == 0) {
    float St = swv[0] + swv[1] + swv[2] + swv[3];
    atomicAdd(&Ssum[b], diag ? St : 2.f * St);
  }
}

// ---------------------------------------------------------------------------
// Kernel 4: finalize. loss_b = -(T/BT) * (S_b/T - sum_i P_i log D_i) / psum_b
// ---------------------------------------------------------------------------
__global__ __launch_bounds__(1024) void finalize_kernel(
    const float* __restrict__ denom, const float* __restrict__ Prow,
    const float* __restrict__ Ssum, float* __restrict__ out) {
  int t = threadIdx.x;
  int b = t >> 8, u = t & 255;
  float P = 0.f, L = 0.f;
#pragma unroll
  for (int q = 0; q < 4; ++q) {
    int s = u + q * 256;
    float p = Prow[b * SSEL + s];
    float D = denom[b * SSEL + s];
    P += p;
    L += p * logf(D > 0.f ? D : 1.f);
  }
  for (int off = 32; off > 0; off >>= 1) {
    P += __shfl_xor(P, off, 64);
    L += __shfl_xor(L, off, 64);
  }
  __shared__ float wP[16], wL[16];
  int lane = t & 63, w = t >> 6;
  if (lane == 0) { wP[w] = P; wL[w] = L; }
  __syncthreads();
  if (t == 0) {
    float total = 0.f, n = 0.f;
    for (int bb = 0; bb < BATCH; ++bb) {
      float psum = wP[4 * bb] + wP[4 * bb + 1] + wP[4 * bb + 2] + wP[4 * bb + 3];
      float lsum = wL[4 * bb] + wL[4 * bb + 1] + wL[4 * bb + 2] + wL[4 * bb + 3];
      if (psum > 0.f) {
        float wls = Ssum[bb] * INV_T - lsum;
        total += -RATIO * wls / psum;
        n += 1.f;
      }
    }
    out[0] = (n > 0.f) ? (total / n) : 0.f;
  }
}

// ---------------------------------------------------------------------------
extern "C" void kernel_launch(void* const* d_in, const int* in_sizes, int n_in,
                              void* d_out, int out_size, void* d_ws, size_t ws_size,
                              hipStream_t stream) {
  const float* feats = (const float*)d_in[0];
  const int*   labels = (const int*)d_in[1];
  const int*   sp     = (const int*)d_in[2];
  const float* w1  = (const float*)d_in[3];
  const float* b1  = (const float*)d_in[4];
  const float* w2  = (const float*)d_in[5];
  const float* b2  = (const float*)d_in[6];
  const float* wa1 = (const float*)d_in[7];
  const float* ba1 = (const float*)d_in[8];
  const float* wa2 = (const float*)d_in[9];
  const float* ba2 = (const float*)d_in[10];
  float* out = (float*)d_out;

  float* W    = (float*)d_ws;
  float* w1p  = W;                      // 65536 f
  float* w2p  = w1p  + 65536;           // 65536 f
  float* wa1p = w2p  + 65536;           // 16384 f
  unsigned short* fnh = (unsigned short*)(wa1p + 16384);  // 1048576 us (16B-aligned)
  unsigned short* fnl = fnh + 1048576;                    // 1048576 us
  float* tw   = (float*)(fnl + 1048576);// 4096 f
  float* denom= tw   + 4096;            // 4096
  float* Prow = denom+ 4096;            // 4096
  float* Ssum = Prow + 4096;            // 4
  int*   idx  = (int*)(Ssum + 4);       // 4096
  int*   selv = idx  + 4096;            // 4096
  int*   tsp  = selv + 4096;            // 4096
  int*   counts = tsp + 4096;           // 100

  pack_weights<<<256, 256, 0, stream>>>(w1, w2, wa1, labels, w1p, w2p, wa1p,
                                        denom, Prow, Ssum, counts);
  select_scatter<<<BATCH * NCHUNK, 1024, 0, stream>>>(labels, sp, counts,
                                                      idx, selv, tsp);
  mlp_kernel<<<(BATCH * SSEL) / RROWS, 256, 0, stream>>>(
      feats, w1p, b1, w2p, b2, wa1p, ba1, wa2, ba2, idx, fnh, fnl, tw);
  sim_kernel<<<dim3(136, BATCH), 256, 0, stream>>>(fnh, fnl, tw, selv, tsp,
                                                   denom, Prow, Ssum);
  finalize_kernel<<<1, 1024, 0, stream>>>(denom, Prow, Ssum, out);
}